// Round 10
// baseline (124.805 us; speedup 1.0000x reference)
//
#include <hip/hip_runtime.h>
#include <math.h>

#define NUM_CLASSES 10
#define GRID_H 80
#define GRID_W 80
#define NCELLS (GRID_H * GRID_W)
#define NBOX 64
#define SEG (1024 * 1024)   // Hs*Ws per (batch[,channel])
#define XBLK 256            // 256 blk * 256 thr * 16 elem == SEG exactly
#define TPB 256

typedef float  f32x4 __attribute__((ext_vector_type(4)));
typedef int    i32x4 __attribute__((ext_vector_type(4)));

// ws layout (doubles):
//  0..7    obj_sum[b]
//  8..15   box_sum[b]
// 16..23   cls_sum[b]
// 24..31   npos[b]
// 32..39   da_sum[b]
// 40..47   da_cnt[b]
// 48..71   rm_focal[b*3+c]
// 72..95   rm_inter[ch]
// 96..119  rm_probsum[ch]
// 120..143 rm_rtsum[ch]
// 144..167 rm_cnt[ch]
#define WS_DOUBLES 168

__device__ __forceinline__ void reduce_atomic(double v, double* gdst, double* smem) {
    #pragma unroll
    for (int off = 32; off > 0; off >>= 1) v += __shfl_down(v, off, 64);
    int lane = threadIdx.x & 63, wid = threadIdx.x >> 6;
    __syncthreads();               // protect smem reuse across successive calls
    if (lane == 0) smem[wid] = v;
    __syncthreads();
    if (threadIdx.x == 0) {
        double s = 0.0;
        int nw = blockDim.x >> 6;
        for (int i = 0; i < nw; i++) s += smem[i];
        atomicAdd(gdst, s);
    }
}

// one element of rm/da math; t in {0,1}; is_rm selects focal weighting
__device__ __forceinline__ void elem_one(float x, int m, bool is_rm,
        float& lsum, float& inter, float& ps, float& ts, float& cnt) {
    const float vf = (m != 255) ? 1.0f : 0.0f;
    const float t  = (m != 255) ? (float)m : 0.0f;
    const float e_ = __expf(-fabsf(x));
    const float sp = __builtin_amdgcn_rcpf(1.0f + e_);
    const float sn = e_ * sp;
    const bool xp = (x >= 0.0f);
    const bool tp = (t > 0.5f);
    const float prob = xp ? sp : sn;          // sigmoid(x)
    const float pt   = (xp == tp) ? sp : sn;  // prob*t + (1-prob)*(1-t)
    const float om   = (xp == tp) ? sn : sp;  // 1 - pt
    const float bce  = -__logf(pt);
    const float fw   = is_rm ? om * om : 1.0f;
    lsum  += vf * fw * bce;
    inter += prob * t;                        // t==0 when invalid
    ps    += vf * prob;
    ts    += t;
    cnt   += vf;
}

#define COMPUTE4(A, B)                                                    \
    do {                                                                  \
        elem_one(A[0], B[0], is_rm, lsum, inter, ps, ts, cnt);            \
        elem_one(A[1], B[1], is_rm, lsum, inter, ps, ts, cnt);            \
        elem_one(A[2], B[2], is_rm, lsum, inter, ps, ts, cnt);            \
        elem_one(A[3], B[3], is_rm, lsum, inter, ps, ts, cnt);            \
    } while (0)

// ---------------- streaming rm+da: nt loads, lane-contiguous, one-shot ----------------
// y in [0,24): rm channel y ; y in [24,32): da batch y-24
__global__ __launch_bounds__(TPB, 4) void stream_kernel(
        const float* __restrict__ da_logits,
        const int*   __restrict__ da_mask,
        const float* __restrict__ rm_logits,
        const int*   __restrict__ rm_mask,
        double* __restrict__ acc) {
    __shared__ double smem[4];
    const int y = blockIdx.y;
    const bool is_rm = (y < 24);
    const float* lbase = is_rm ? rm_logits + (size_t)y * SEG
                               : da_logits + (size_t)(y - 24) * SEG;
    const int*   mbase = is_rm ? rm_mask + (size_t)y * SEG
                               : da_mask + (size_t)(y - 24) * SEG;
    const f32x4* lp = (const f32x4*)lbase;
    const i32x4* mp = (const i32x4*)mbase;

    // lane-contiguous: each load instr covers one contiguous 1KB segment;
    // nontemporal: no L2/L3 allocation -> no cache thrash, HBM-stream latency
    const int i0 = blockIdx.x * (TPB * 4) + threadIdx.x;
    f32x4 a0 = __builtin_nontemporal_load(lp + i0);
    f32x4 a1 = __builtin_nontemporal_load(lp + i0 + TPB);
    f32x4 a2 = __builtin_nontemporal_load(lp + i0 + 2 * TPB);
    f32x4 a3 = __builtin_nontemporal_load(lp + i0 + 3 * TPB);
    i32x4 b0 = __builtin_nontemporal_load(mp + i0);
    i32x4 b1 = __builtin_nontemporal_load(mp + i0 + TPB);
    i32x4 b2 = __builtin_nontemporal_load(mp + i0 + 2 * TPB);
    i32x4 b3 = __builtin_nontemporal_load(mp + i0 + 3 * TPB);

    float lsum = 0.f, inter = 0.f, ps = 0.f, ts = 0.f, cnt = 0.f;
    COMPUTE4(a0, b0);
    COMPUTE4(a1, b1);
    COMPUTE4(a2, b2);
    COMPUTE4(a3, b3);

    if (is_rm) {
        reduce_atomic((double)lsum,  &acc[48 + y],  smem);
        reduce_atomic((double)inter, &acc[72 + y],  smem);
        reduce_atomic((double)ps,    &acc[96 + y],  smem);
        reduce_atomic((double)ts,    &acc[120 + y], smem);
        reduce_atomic((double)cnt,   &acc[144 + y], smem);
    } else {
        reduce_atomic((double)lsum, &acc[32 + (y - 24)], smem);
        reduce_atomic((double)cnt,  &acc[40 + (y - 24)], smem);
    }
}

// ---------------- det (OD) ----------------
__global__ void det_kernel(const float* __restrict__ det_logits,
                           const float* __restrict__ det_yolo,
                           double* __restrict__ acc) {
    __shared__ float gt[NBOX * 5];
    __shared__ double smem[4];
    const int b = blockIdx.y;
    const int tid = threadIdx.x;
    const float* g = det_yolo + (size_t)b * NBOX * 5;
    for (int i = tid; i < NBOX * 5; i += blockDim.x) gt[i] = g[i];
    __syncthreads();

    const int cell = blockIdx.x * TPB + tid;   // 25 * 256 == 6400 exactly

    int win = -1;   // last valid box mapping to this cell wins
    #pragma unroll 4
    for (int n = 0; n < NBOX; n++) {
        const int cls = (int)gt[n * 5 + 0];
        const bool valid = (cls >= 0) && (cls < NUM_CLASSES) &&
                           (gt[n * 5 + 3] > 0.0f) && (gt[n * 5 + 4] > 0.0f);
        if (valid) {
            const float cx = fminf(fmaxf(gt[n * 5 + 1], 0.0f), 1.0f);
            const float cy = fminf(fmaxf(gt[n * 5 + 2], 0.0f), 1.0f);
            const int gx = min((int)(cx * (float)GRID_W), GRID_W - 1);
            const int gy = min((int)(cy * (float)GRID_H), GRID_H - 1);
            if (gy * GRID_W + gx == cell) win = n;
        }
    }
    const float* dl = det_logits + (size_t)b * 15 * NCELLS;
    const float x_obj = dl[4 * NCELLS + cell];
    const float tobj = (win >= 0) ? 1.0f : 0.0f;
    float obj;
    {
        const float e  = __expf(-fabsf(x_obj));
        const float sp = __builtin_amdgcn_rcpf(1.0f + e);
        const float sn = e * sp;
        obj = -__logf(((x_obj >= 0.0f) == (tobj > 0.5f)) ? sp : sn);
    }
    float boxl = 0.0f, clsl = 0.0f, posn = 0.0f;
    if (win >= 0) {
        posn = 1.0f;
        #pragma unroll
        for (int k = 0; k < 4; k++) {
            const float xb = dl[k * NCELLS + cell];
            const float e = __expf(-fabsf(xb));
            const float sp = __builtin_amdgcn_rcpf(1.0f + e);
            const float pb = (xb >= 0.0f) ? sp : e * sp;
            const float tc = fminf(fmaxf(gt[win * 5 + 1 + k], 0.0f), 1.0f);
            const float d = fabsf(pb - tc);
            boxl += (d < 1.0f) ? 0.5f * d * d : d - 0.5f;
        }
        float lx[NUM_CLASSES];
        float mx = -INFINITY;
        #pragma unroll
        for (int c = 0; c < NUM_CLASSES; c++) {
            lx[c] = dl[(5 + c) * NCELLS + cell];
            mx = fmaxf(mx, lx[c]);
        }
        float se = 0.0f;
        #pragma unroll
        for (int c = 0; c < NUM_CLASSES; c++) se += __expf(lx[c] - mx);
        const int tcl = (int)gt[win * 5 + 0];
        clsl = -(lx[tcl] - mx - __logf(se));
    }
    reduce_atomic((double)obj,  &acc[0 + b],  smem);
    reduce_atomic((double)boxl, &acc[8 + b],  smem);
    reduce_atomic((double)clsl, &acc[16 + b], smem);
    reduce_atomic((double)posn, &acc[24 + b], smem);
}

// ---------------- finalize ----------------
__global__ void final_kernel(const double* __restrict__ acc,
                             const int* __restrict__ has_det,
                             const int* __restrict__ has_da,
                             const int* __restrict__ has_rm,
                             float* __restrict__ out, int B) {
    if (threadIdx.x != 0 || blockIdx.x != 0) return;
    double od_num = 0.0, wsum = 0.0;
    for (int b = 0; b < B; b++) {
        const double np_ = fmax(acc[24 + b], 1.0);
        const double obj_b = acc[0 + b] / (double)NCELLS;
        const double box_b = acc[8 + b] / (np_ * 4.0);
        const double cls_b = acc[16 + b] / np_;
        const double w = (double)has_det[b];
        od_num += (obj_b + box_b + cls_b) * w;
        wsum += w;
    }
    const double od = od_num / fmax(wsum, 1.0);

    double da_num = 0.0, daw = 0.0;
    for (int b = 0; b < B; b++) {
        const double c = acc[40 + b];
        const double da_b = acc[32 + b] / fmax(c, 1.0);
        const double w = (double)has_da[b] * (c > 0.0 ? 1.0 : 0.0);
        da_num += da_b * w;
        daw += w;
    }
    const double da = da_num / fmax(daw, 1.0);

    double rm_num = 0.0, rmw = 0.0;
    for (int ch = 0; ch < 3 * B; ch++) {
        const double c = acc[144 + ch];
        const double focal = acc[48 + ch] / fmax(c, 1.0);
        const double dice = 1.0 - (2.0 * acc[72 + ch] + 1e-6) /
                                  (acc[96 + ch] + acc[120 + ch] + 1e-6);
        const double w = (double)has_rm[ch] * (c > 0.0 ? 1.0 : 0.0);
        rm_num += (focal + dice) * w;
        rmw += w;
    }
    const double rm = rm_num / fmax(rmw, 1.0);

    const double total = od + da + 2.0 * rm;
    out[0] = (float)total;
    out[1] = (float)od;
    out[2] = (float)da;
    out[3] = (float)rm;
}

extern "C" void kernel_launch(void* const* d_in, const int* in_sizes, int n_in,
                              void* d_out, int out_size, void* d_ws, size_t ws_size,
                              hipStream_t stream) {
    const float* det_logits = (const float*)d_in[0];
    const float* det_yolo   = (const float*)d_in[1];
    const float* da_logits  = (const float*)d_in[2];
    const int*   da_mask    = (const int*)d_in[3];
    const float* rm_logits  = (const float*)d_in[4];
    const int*   rm_mask    = (const int*)d_in[5];
    const int*   has_det    = (const int*)d_in[6];
    const int*   has_da     = (const int*)d_in[7];
    const int*   has_rm     = (const int*)d_in[8];
    float* out = (float*)d_out;
    double* acc = (double*)d_ws;

    const int B = in_sizes[6];   // 8

    hipMemsetAsync(acc, 0, WS_DOUBLES * sizeof(double), stream);

    det_kernel<<<dim3(NCELLS / TPB, B), TPB, 0, stream>>>(det_logits, det_yolo, acc);
    stream_kernel<<<dim3(XBLK, 32), TPB, 0, stream>>>(
        da_logits, da_mask, rm_logits, rm_mask, acc);
    final_kernel<<<1, 64, 0, stream>>>(acc, has_det, has_da, has_rm, out, B);
}

// Round 11
// 87.389 us; speedup vs baseline: 1.4282x; 1.4282x over previous
//
#include <hip/hip_runtime.h>
#include <math.h>

#define NUM_CLASSES 10
#define GRID_H 80
#define GRID_W 80
#define NCELLS (GRID_H * GRID_W)
#define NBOX 64
#define SEG (1024 * 1024)   // Hs*Ws per (batch[,channel])
#define XBLK 64
#define TPB 256

typedef float  f32x4 __attribute__((ext_vector_type(4)));
typedef int    i32x4 __attribute__((ext_vector_type(4)));

// ws layout (doubles):
//  0..7    obj_sum[b]
//  8..15   box_sum[b]
// 16..23   cls_sum[b]
// 24..31   npos[b]
// 32..39   da_sum[b]
// 40..47   da_cnt[b]
// 48..71   rm_focal[b*3+c]
// 72..95   rm_inter[ch]
// 96..119  rm_probsum[ch]
// 120..143 rm_rtsum[ch]
// 144..167 rm_cnt[ch]
#define WS_DOUBLES 168

__device__ __forceinline__ void reduce_atomic(double v, double* gdst, double* smem) {
    #pragma unroll
    for (int off = 32; off > 0; off >>= 1) v += __shfl_down(v, off, 64);
    int lane = threadIdx.x & 63, wid = threadIdx.x >> 6;
    __syncthreads();               // protect smem reuse across successive calls
    if (lane == 0) smem[wid] = v;
    __syncthreads();
    if (threadIdx.x == 0) {
        double s = 0.0;
        int nw = blockDim.x >> 6;
        for (int i = 0; i < nw; i++) s += smem[i];
        atomicAdd(gdst, s);
    }
}

// one element of rm/da math; t in {0,1}; IS_RM selects focal weighting
template<bool IS_RM>
__device__ __forceinline__ void elem_one(float x, int m,
        float& lsum, float& inter, float& ps, float& ts, float& cnt) {
    const float vf = (m != 255) ? 1.0f : 0.0f;
    const float t  = (m != 255) ? (float)m : 0.0f;
    const float e_ = __expf(-fabsf(x));
    const float sp = __builtin_amdgcn_rcpf(1.0f + e_);
    const float sn = e_ * sp;
    const bool xp = (x >= 0.0f);
    const bool tp = (t > 0.5f);
    const float prob = xp ? sp : sn;          // sigmoid(x)
    const float pt   = (xp == tp) ? sp : sn;  // prob*t + (1-prob)*(1-t)
    const float om   = (xp == tp) ? sn : sp;  // 1 - pt
    const float bce  = -__logf(pt);
    const float fw   = IS_RM ? om * om : 1.0f;
    lsum  += vf * fw * bce;
    inter += prob * t;                        // t==0 when invalid
    ps    += vf * prob;
    ts    += t;
    cnt   += vf;
}

#define COMPUTE4(A, B)                                                    \
    do {                                                                  \
        elem_one<IS_RM>(A[0], B[0], lsum, inter, ps, ts, cnt);            \
        elem_one<IS_RM>(A[1], B[1], lsum, inter, ps, ts, cnt);            \
        elem_one<IS_RM>(A[2], B[2], lsum, inter, ps, ts, cnt);            \
        elem_one<IS_RM>(A[3], B[3], lsum, inter, ps, ts, cnt);            \
    } while (0)

// R4 grid-stride loop; NT selects nontemporal (no-allocate) loads.
// rm keeps normal loads -> stays L3-resident across graph replays;
// da is NT -> streams from HBM without evicting rm from the 256MB L3.
template<bool IS_RM, bool NT>
__device__ __forceinline__ void stream_loop(
        const float* __restrict__ lbase, const int* __restrict__ mbase,
        float& lsum, float& inter, float& ps, float& ts, float& cnt) {
    const int stride = XBLK * TPB * 16;
    for (int e = (blockIdx.x * TPB + threadIdx.x) * 16; e < SEG; e += stride) {
        const f32x4* lp = (const f32x4*)(lbase + e);
        const i32x4* mp = (const i32x4*)(mbase + e);
        f32x4 a0, a1, a2, a3;
        i32x4 b0, b1, b2, b3;
        if constexpr (NT) {
            a0 = __builtin_nontemporal_load(lp + 0);
            a1 = __builtin_nontemporal_load(lp + 1);
            a2 = __builtin_nontemporal_load(lp + 2);
            a3 = __builtin_nontemporal_load(lp + 3);
            b0 = __builtin_nontemporal_load(mp + 0);
            b1 = __builtin_nontemporal_load(mp + 1);
            b2 = __builtin_nontemporal_load(mp + 2);
            b3 = __builtin_nontemporal_load(mp + 3);
        } else {
            a0 = lp[0]; a1 = lp[1]; a2 = lp[2]; a3 = lp[3];
            b0 = mp[0]; b1 = mp[1]; b2 = mp[2]; b3 = mp[3];
        }
        COMPUTE4(a0, b0);
        COMPUTE4(a1, b1);
        COMPUTE4(a2, b2);
        COMPUTE4(a3, b3);
    }
}

// ---------------- streaming rm+da ----------------
// y in [0,24): rm channel y (normal loads) ; y in [24,32): da batch y-24 (nt loads)
__global__ __launch_bounds__(TPB, 8) void stream_kernel(
        const float* __restrict__ da_logits,
        const int*   __restrict__ da_mask,
        const float* __restrict__ rm_logits,
        const int*   __restrict__ rm_mask,
        double* __restrict__ acc) {
    __shared__ double smem[4];
    const int y = blockIdx.y;
    float lsum = 0.f, inter = 0.f, ps = 0.f, ts = 0.f, cnt = 0.f;
    if (y < 24) {
        constexpr bool IS_RM = true;
        stream_loop<true, false>(rm_logits + (size_t)y * SEG,
                                 rm_mask + (size_t)y * SEG,
                                 lsum, inter, ps, ts, cnt);
        (void)IS_RM;
        reduce_atomic((double)lsum,  &acc[48 + y],  smem);
        reduce_atomic((double)inter, &acc[72 + y],  smem);
        reduce_atomic((double)ps,    &acc[96 + y],  smem);
        reduce_atomic((double)ts,    &acc[120 + y], smem);
        reduce_atomic((double)cnt,   &acc[144 + y], smem);
    } else {
        const int b = y - 24;
        stream_loop<false, true>(da_logits + (size_t)b * SEG,
                                 da_mask + (size_t)b * SEG,
                                 lsum, inter, ps, ts, cnt);
        reduce_atomic((double)lsum, &acc[32 + b], smem);
        reduce_atomic((double)cnt,  &acc[40 + b], smem);
    }
}

// ---------------- det (OD) ----------------
__global__ void det_kernel(const float* __restrict__ det_logits,
                           const float* __restrict__ det_yolo,
                           double* __restrict__ acc) {
    __shared__ float gt[NBOX * 5];
    __shared__ double smem[4];
    const int b = blockIdx.y;
    const int tid = threadIdx.x;
    const float* g = det_yolo + (size_t)b * NBOX * 5;
    for (int i = tid; i < NBOX * 5; i += blockDim.x) gt[i] = g[i];
    __syncthreads();

    const int cell = blockIdx.x * TPB + tid;   // 25 * 256 == 6400 exactly

    int win = -1;   // last valid box mapping to this cell wins
    #pragma unroll 4
    for (int n = 0; n < NBOX; n++) {
        const int cls = (int)gt[n * 5 + 0];
        const bool valid = (cls >= 0) && (cls < NUM_CLASSES) &&
                           (gt[n * 5 + 3] > 0.0f) && (gt[n * 5 + 4] > 0.0f);
        if (valid) {
            const float cx = fminf(fmaxf(gt[n * 5 + 1], 0.0f), 1.0f);
            const float cy = fminf(fmaxf(gt[n * 5 + 2], 0.0f), 1.0f);
            const int gx = min((int)(cx * (float)GRID_W), GRID_W - 1);
            const int gy = min((int)(cy * (float)GRID_H), GRID_H - 1);
            if (gy * GRID_W + gx == cell) win = n;
        }
    }
    const float* dl = det_logits + (size_t)b * 15 * NCELLS;
    const float x_obj = dl[4 * NCELLS + cell];
    const float tobj = (win >= 0) ? 1.0f : 0.0f;
    float obj;
    {
        const float e  = __expf(-fabsf(x_obj));
        const float sp = __builtin_amdgcn_rcpf(1.0f + e);
        const float sn = e * sp;
        obj = -__logf(((x_obj >= 0.0f) == (tobj > 0.5f)) ? sp : sn);
    }
    float boxl = 0.0f, clsl = 0.0f, posn = 0.0f;
    if (win >= 0) {
        posn = 1.0f;
        #pragma unroll
        for (int k = 0; k < 4; k++) {
            const float xb = dl[k * NCELLS + cell];
            const float e = __expf(-fabsf(xb));
            const float sp = __builtin_amdgcn_rcpf(1.0f + e);
            const float pb = (xb >= 0.0f) ? sp : e * sp;
            const float tc = fminf(fmaxf(gt[win * 5 + 1 + k], 0.0f), 1.0f);
            const float d = fabsf(pb - tc);
            boxl += (d < 1.0f) ? 0.5f * d * d : d - 0.5f;
        }
        float lx[NUM_CLASSES];
        float mx = -INFINITY;
        #pragma unroll
        for (int c = 0; c < NUM_CLASSES; c++) {
            lx[c] = dl[(5 + c) * NCELLS + cell];
            mx = fmaxf(mx, lx[c]);
        }
        float se = 0.0f;
        #pragma unroll
        for (int c = 0; c < NUM_CLASSES; c++) se += __expf(lx[c] - mx);
        const int tcl = (int)gt[win * 5 + 0];
        clsl = -(lx[tcl] - mx - __logf(se));
    }
    reduce_atomic((double)obj,  &acc[0 + b],  smem);
    reduce_atomic((double)boxl, &acc[8 + b],  smem);
    reduce_atomic((double)clsl, &acc[16 + b], smem);
    reduce_atomic((double)posn, &acc[24 + b], smem);
}

// ---------------- finalize ----------------
__global__ void final_kernel(const double* __restrict__ acc,
                             const int* __restrict__ has_det,
                             const int* __restrict__ has_da,
                             const int* __restrict__ has_rm,
                             float* __restrict__ out, int B) {
    if (threadIdx.x != 0 || blockIdx.x != 0) return;
    double od_num = 0.0, wsum = 0.0;
    for (int b = 0; b < B; b++) {
        const double np_ = fmax(acc[24 + b], 1.0);
        const double obj_b = acc[0 + b] / (double)NCELLS;
        const double box_b = acc[8 + b] / (np_ * 4.0);
        const double cls_b = acc[16 + b] / np_;
        const double w = (double)has_det[b];
        od_num += (obj_b + box_b + cls_b) * w;
        wsum += w;
    }
    const double od = od_num / fmax(wsum, 1.0);

    double da_num = 0.0, daw = 0.0;
    for (int b = 0; b < B; b++) {
        const double c = acc[40 + b];
        const double da_b = acc[32 + b] / fmax(c, 1.0);
        const double w = (double)has_da[b] * (c > 0.0 ? 1.0 : 0.0);
        da_num += da_b * w;
        daw += w;
    }
    const double da = da_num / fmax(daw, 1.0);

    double rm_num = 0.0, rmw = 0.0;
    for (int ch = 0; ch < 3 * B; ch++) {
        const double c = acc[144 + ch];
        const double focal = acc[48 + ch] / fmax(c, 1.0);
        const double dice = 1.0 - (2.0 * acc[72 + ch] + 1e-6) /
                                  (acc[96 + ch] + acc[120 + ch] + 1e-6);
        const double w = (double)has_rm[ch] * (c > 0.0 ? 1.0 : 0.0);
        rm_num += (focal + dice) * w;
        rmw += w;
    }
    const double rm = rm_num / fmax(rmw, 1.0);

    const double total = od + da + 2.0 * rm;
    out[0] = (float)total;
    out[1] = (float)od;
    out[2] = (float)da;
    out[3] = (float)rm;
}

extern "C" void kernel_launch(void* const* d_in, const int* in_sizes, int n_in,
                              void* d_out, int out_size, void* d_ws, size_t ws_size,
                              hipStream_t stream) {
    const float* det_logits = (const float*)d_in[0];
    const float* det_yolo   = (const float*)d_in[1];
    const float* da_logits  = (const float*)d_in[2];
    const int*   da_mask    = (const int*)d_in[3];
    const float* rm_logits  = (const float*)d_in[4];
    const int*   rm_mask    = (const int*)d_in[5];
    const int*   has_det    = (const int*)d_in[6];
    const int*   has_da     = (const int*)d_in[7];
    const int*   has_rm     = (const int*)d_in[8];
    float* out = (float*)d_out;
    double* acc = (double*)d_ws;

    const int B = in_sizes[6];   // 8

    hipMemsetAsync(acc, 0, WS_DOUBLES * sizeof(double), stream);

    det_kernel<<<dim3(NCELLS / TPB, B), TPB, 0, stream>>>(det_logits, det_yolo, acc);
    stream_kernel<<<dim3(XBLK, 32), TPB, 0, stream>>>(
        da_logits, da_mask, rm_logits, rm_mask, acc);
    final_kernel<<<1, 64, 0, stream>>>(acc, has_det, has_da, has_rm, out, B);
}